// Round 19
// baseline (39.928 us; speedup 1.0000x reference)
//
#include <hip/hip_runtime.h>

#define NEG_SLOPE 0.2f
#define EPS 1e-6f

// x: [B=4, C=64, V=3, N=32768] f32, W: [64,64] f32, out like x
// d[o,v,n] = sum_i W[o,i]*x[i,v,n]; out = dot>=0 ? x : x - 0.8*(dot/(dnsq+eps))*d
// bf16 MFMA (A=W frag, B=x frag), hi/lo 3-product split; accx identity-MFMA
// epilogue (R18). Staging via global_load_lds DMA into a raw-f32 double
// buffer (R11 mechanics): no VGPR round-trip, no pack VALU, no ds_write.
// Bank swizzle on the GLOBAL source chunk: c ^= ((i>>3)&1)<<2 -> consumer
// col = n ^ ((hi&1)<<4), 2-way (free).

#define C_CH 64
#define V_DIM 3
#define N_FULL 32768
#define NT 32
#define THREADS 256
#define TPB 4

typedef __attribute__((ext_vector_type(8))) short bf16x8;
typedef __attribute__((ext_vector_type(4))) float f32x4;

__device__ __forceinline__ ushort f2bf(float f) {
    union { float f; unsigned u; } v; v.f = f;
    unsigned r = v.u + 0x7FFFu + ((v.u >> 16) & 1u);  // RNE
    return (ushort)(r >> 16);
}
__device__ __forceinline__ float bf2f(ushort s) {
    union { unsigned u; float f; } v; v.u = ((unsigned)s) << 16; return v.f;
}
__device__ __forceinline__ unsigned f2u(float f) {
    union { float f; unsigned u; } v; v.f = f; return v.u;
}
__device__ __forceinline__ float u2f(unsigned u) {
    union { unsigned u; float f; } v; v.u = u; return v.f;
}

__global__ __launch_bounds__(THREADS, 3)
void vn_dma_pipe(const float* __restrict__ x,
                 const float* __restrict__ Wf,
                 float* __restrict__ out) {
    // raw f32 double buffer, row r = 3*i+v (global order), 32 cols. 2 x 24 KB.
    __shared__ float xs[2][V_DIM * C_CH * NT];

    const int t     = threadIdx.x;
    const int tile0 = blockIdx.x * TPB;          // 4096 tiles total, 1024 blocks
    const int b     = tile0 >> 10;               // batch (blocks never straddle)
    const float* xbase = x   + (size_t)b * (C_CH * V_DIM * N_FULL);
    float*       obase = out + (size_t)b * (C_CH * V_DIM * N_FULL);

    const int lane = t & 63;
    const int w    = t >> 6;   // 0..3
    const int wo   = w >> 1;   // o-half -> 32 channels (via m loop)
    const int wn   = w & 1;    // n-half -> 16 cols
    const int l4   = lane & 15;
    const int hi   = lane >> 4;

    // DMA staging geometry: slot = t + it*256 (it 0..5), 1536 slots x 16B.
    // LDS dest linear: byte = slot*16 (wave-uniform base + lane*16).
    // slot -> global row r = slot>>3, chunk c = slot&7; source chunk
    // pre-swizzled: c ^ ((i>>3)&1)<<2 where i = r/3.
    const int slot_r[6] = { (t + 0*THREADS) >> 3, (t + 1*THREADS) >> 3,
                            (t + 2*THREADS) >> 3, (t + 3*THREADS) >> 3,
                            (t + 4*THREADS) >> 3, (t + 5*THREADS) >> 3 };

    // ---- A fragments (W): row o = wo*32+m*16+l4, k = kh*32+hi*8+j; RNE split
    bf16x8 Ah[2][2], Al[2][2];
    #pragma unroll
    for (int m = 0; m < 2; ++m)
        #pragma unroll
        for (int kh = 0; kh < 2; ++kh) {
            const float* wp = Wf + (size_t)(wo * 32 + m * 16 + l4) * C_CH + kh * 32 + hi * 8;
            float4 wa = *(const float4*)wp;
            float4 wb = *(const float4*)(wp + 4);
            float wf[8] = {wa.x, wa.y, wa.z, wa.w, wb.x, wb.y, wb.z, wb.w};
            bf16x8 h, l;
            #pragma unroll
            for (int j = 0; j < 8; ++j) {
                ushort hb = f2bf(wf[j]);
                h[j] = (short)hb;
                l[j] = (short)f2bf(wf[j] - bf2f(hb));
            }
            Ah[m][kh] = h; Al[m][kh] = l;
        }

    // ---- identity A-fragments: Aid_m[row][k] = (k == m*16+row)
    bf16x8 Aid0, Aid1;
    {
        const int j1 = l4 & 7;
        const bool h0 = (hi == (l4 >> 3));
        const bool h1 = (hi == 2 + (l4 >> 3));
        #pragma unroll
        for (int j = 0; j < 8; ++j) {
            Aid0[j] = (short)((h0 && j == j1) ? 0x3F80 : 0);
            Aid1[j] = (short)((h1 && j == j1) ? 0x3F80 : 0);
        }
    }

    // ---- DMA-stage a tile into buffer bf
    auto stage = [&](int tile, int bf) {
        const float* xb = xbase + ((tile & 1023) << 5);
        #pragma unroll
        for (int it = 0; it < 6; ++it) {
            int slot = t + it * THREADS;
            int r    = slot_r[it];
            int c    = slot & 7;
            int i    = (r * 171) >> 9;                 // r/3 (exact r<768)
            int cs   = c ^ (((i >> 3) & 1) << 2);      // swizzled source chunk
            const float* g = xb + (size_t)r * N_FULL + (cs << 2);
            void* l = (char*)&xs[bf][0] + (size_t)slot * 16;
            __builtin_amdgcn_global_load_lds(
                (const __attribute__((address_space(1))) unsigned*)g,
                (__attribute__((address_space(3))) unsigned*)l, 16, 0, 0);
        }
    };

    // ---- prologue: DMA tile0 -> buf0 (barrier below drains vmcnt)
    stage(tile0, 0);
    __syncthreads();

    const int acol = (wn * 16 + l4) ^ ((hi & 1) << 4);  // const per lane
    const int n    = wn * 16 + l4;

    #pragma unroll
    for (int tt = 0; tt < TPB; ++tt) {
        const int cur = tt & 1;
        const int n0c = ((tile0 + tt) & 1023) << 5;

        // ---- issue NEXT tile's DMA first (flies under compute; completes
        // by the barrier at the end of this iteration)
        if (tt + 1 < TPB) stage(tile0 + tt + 1, cur ^ 1);

        // ---- compute tile tt from xs[cur]; accx = exact-ish x via identity
        f32x4 acc[2][3], accx[2][3];
        #pragma unroll
        for (int m = 0; m < 2; ++m)
            #pragma unroll
            for (int v = 0; v < 3; ++v) {
                acc[m][v]  = (f32x4){0.f, 0.f, 0.f, 0.f};
                accx[m][v] = (f32x4){0.f, 0.f, 0.f, 0.f};
            }

        #pragma unroll
        for (int v = 0; v < 3; ++v) {
            #pragma unroll
            for (int kh = 0; kh < 2; ++kh) {
                const int ib = kh * 32 + hi * 8;
                float f[8];
                #pragma unroll
                for (int j = 0; j < 8; ++j)
                    f[j] = xs[cur][(3 * (ib + j) + v) * NT + acol];
                // hi = truncated bf16 (perm), lo = trunc(f - hi) (exact resid)
                union { bf16x8 v8; unsigned d[4]; } BH, BL;
                unsigned rl[8];
                #pragma unroll
                for (int j = 0; j < 8; ++j)
                    rl[j] = f2u(f[j] - u2f(f2u(f[j]) & 0xffff0000u));
                #pragma unroll
                for (int q = 0; q < 4; ++q) {
                    BH.d[q] = __builtin_amdgcn_perm(f2u(f[2 * q + 1]), f2u(f[2 * q]), 0x07060302u);
                    BL.d[q] = __builtin_amdgcn_perm(rl[2 * q + 1], rl[2 * q], 0x07060302u);
                }
                #pragma unroll
                for (int m = 0; m < 2; ++m) {
                    acc[m][v] = __builtin_amdgcn_mfma_f32_16x16x32_bf16(Ah[m][kh], BH.v8, acc[m][v], 0, 0, 0);
                    acc[m][v] = __builtin_amdgcn_mfma_f32_16x16x32_bf16(Ah[m][kh], BL.v8, acc[m][v], 0, 0, 0);
                    acc[m][v] = __builtin_amdgcn_mfma_f32_16x16x32_bf16(Al[m][kh], BH.v8, acc[m][v], 0, 0, 0);
                }
                if (kh == wo) {  // wave-uniform: identity block at kh==wo
                    accx[0][v] = __builtin_amdgcn_mfma_f32_16x16x32_bf16(Aid0, BH.v8, accx[0][v], 0, 0, 0);
                    accx[0][v] = __builtin_amdgcn_mfma_f32_16x16x32_bf16(Aid0, BL.v8, accx[0][v], 0, 0, 0);
                    accx[1][v] = __builtin_amdgcn_mfma_f32_16x16x32_bf16(Aid1, BH.v8, accx[1][v], 0, 0, 0);
                    accx[1][v] = __builtin_amdgcn_mfma_f32_16x16x32_bf16(Aid1, BL.v8, accx[1][v], 0, 0, 0);
                }
            }
        }

        // ---- epilogue: C/D col=l4 (n), row=hi*4+rr; x from accx
        float* ob = obase + n0c + n;
        #pragma unroll
        for (int m = 0; m < 2; ++m) {
            #pragma unroll
            for (int rr = 0; rr < 4; ++rr) {
                const int o = wo * 32 + m * 16 + hi * 4 + rr;
                float xv[3], dv[3];
                #pragma unroll
                for (int v = 0; v < 3; ++v) {
                    xv[v] = accx[m][v][rr];
                    dv[v] = acc[m][v][rr];
                }
                float dot  = xv[0] * dv[0] + xv[1] * dv[1] + xv[2] * dv[2];
                float dnsq = dv[0] * dv[0] + dv[1] * dv[1] + dv[2] * dv[2];
                float f = (1.0f - NEG_SLOPE) * dot * __builtin_amdgcn_rcpf(dnsq + EPS);
                f = (dot >= 0.f) ? 0.f : f;
                float o0 = fmaf(-f, dv[0], xv[0]);
                float o1 = fmaf(-f, dv[1], xv[1]);
                float o2 = fmaf(-f, dv[2], xv[2]);
                float* op = ob + (size_t)o * (V_DIM * N_FULL);
                op[0 * N_FULL] = o0;
                op[1 * N_FULL] = o1;
                op[2 * N_FULL] = o2;
            }
        }

        __syncthreads();   // drains DMA vmcnt + fences buffer swap
    }
}

extern "C" void kernel_launch(void* const* d_in, const int* in_sizes, int n_in,
                              void* d_out, int out_size, void* d_ws, size_t ws_size,
                              hipStream_t stream) {
    const float* x = (const float*)d_in[0];
    const float* W = (const float*)d_in[1];
    float* out = (float*)d_out;

    const int B = 4;
    const int blocks = B * (N_FULL / NT) / TPB;  // 1024
    vn_dma_pipe<<<blocks, THREADS, 0, stream>>>(x, W, out);
}